// Round 3
// baseline (394.056 us; speedup 1.0000x reference)
//
#include <hip/hip_runtime.h>
#include <hip/hip_bf16.h>

#define TROWS 1048576
#define RPB   256                    // rows per block (chunk)
#define NCHUNK (TROWS / RPB)         // 4096
#define PUBLISHED 0x80000000u

typedef float f32x4  __attribute__((ext_vector_type(4)));
typedef short bf16x8 __attribute__((ext_vector_type(8)));
typedef short bf16x4 __attribute__((ext_vector_type(4)));

#define MFMA(a, b, c) __builtin_amdgcn_mfma_f32_16x16x32_bf16(a, b, c, 0, 0, 0)

__device__ __forceinline__ short f2bf(float v) {
    __hip_bfloat16 b = __float2bfloat16(v);
    return __builtin_bit_cast(short, b);
}
__device__ __forceinline__ float bf2f(short s) {
    unsigned u = ((unsigned)(unsigned short)s) << 16;
    return __builtin_bit_cast(float, u);
}

// k-map for ALL A/B fragments: kappa(g,j) = j<4 ? 4g+j : 16+4g+(j-4)
// ---------------------------------------------------------------------------
// Prep: weights -> bf16 fragment order (identical to round-2, verified).
//   W0a: frag 0..15 (ks*8+nt)   W0b: 16..23 (ks*2+ot)
//   W1a: 24..47 (ks*8+nt)       W1b: 48..55 (ks*2+ot)
// ---------------------------------------------------------------------------
__global__ __launch_bounds__(64) void prep_kernel(
    const float* __restrict__ W0a, const float* __restrict__ W0b,
    const float* __restrict__ W1a, const float* __restrict__ W1b,
    bf16x8* __restrict__ frag)
{
    const int fid = blockIdx.x, l = threadIdx.x, c = l & 15, g = l >> 4;
    const float* W; int N, ks, nt;
    if (fid < 16)      { W = W0a; N = 128; ks = fid >> 3;        nt = fid & 7; }
    else if (fid < 24) { W = W0b; N = 32;  ks = (fid - 16) >> 1; nt = (fid - 16) & 1; }
    else if (fid < 48) { W = W1a; N = 128; ks = (fid - 24) >> 3; nt = (fid - 24) & 7; }
    else               { W = W1b; N = 32;  ks = (fid - 48) >> 1; nt = (fid - 48) & 1; }
    bf16x8 f;
    #pragma unroll
    for (int j = 0; j < 8; ++j) {
        const int k = 32 * ks + ((j < 4) ? (4 * g + j) : (16 + 4 * g + (j - 4)));
        f[j] = f2bf(W[k * N + 16 * nt + c]);
    }
    frag[fid * 64 + l] = f;
}

// ---------------------------------------------------------------------------
// Fused kernel: chunk b = rows [256b, 256b+256)
//   phase A: MLP0 -> out0b (bf16, masked); publish chunk agg (release, agent)
//   scan:    excl_b = first nonzero published agg going back (1 hop in practice)
//   phase B: per-row idx, gather filled, MLP1, blend, store out (fp32)
// x fragments stay in VGPRs across both phases (x read exactly once).
// ---------------------------------------------------------------------------
__global__ __launch_bounds__(256, 2) void fused_kernel(
    const float* __restrict__ x, const int* __restrict__ topk,
    const float* __restrict__ wts,
    const float* __restrict__ b0a, const float* __restrict__ b0b,
    const float* __restrict__ b1a, const float* __restrict__ b1b,
    const bf16x8* __restrict__ frag,
    unsigned* __restrict__ state,
    unsigned short* __restrict__ out0b,
    float* __restrict__ out)
{
    const int b = blockIdx.x;
    const int tid = threadIdx.x, wv = tid >> 6, l = tid & 63, c = l & 15, g = l >> 4;

    __shared__ int smax[4], wtot[4];
    __shared__ int sExcl;

    // --- scan inputs for own row ---
    const int t = b * RPB + tid;
    const int2 tko = ((const int2*)topk)[t];
    const bool m0o = (tko.x == 0) || (tko.y == 0);
    int m = m0o ? t : 0;
    int s = m;
    #pragma unroll
    for (int off = 1; off < 64; off <<= 1) {          // wave-local inclusive cummax
        int u = __shfl_up(s, off, 64);
        if (l >= off) s = max(s, u);
    }
    if (l == 63) wtot[wv] = s;
    #pragma unroll
    for (int off = 32; off; off >>= 1) m = max(m, __shfl_down(m, off, 64));
    if (l == 0) smax[wv] = m;

    // --- load x fragments for all 4 row-tiles (the only x read) ---
    bf16x8 xf[4][2];
    #pragma unroll
    for (int rt = 0; rt < 4; ++rt) {
        const int row = b * RPB + wv * 64 + rt * 16 + c;
        const float* xr = x + (size_t)row * 64;
        #pragma unroll
        for (int ks = 0; ks < 2; ++ks) {
            f32x4 a  = *(const f32x4*)(xr + 32 * ks + 4 * g);
            f32x4 bb = *(const f32x4*)(xr + 32 * ks + 16 + 4 * g);
            #pragma unroll
            for (int j = 0; j < 4; ++j) { xf[rt][ks][j] = f2bf(a[j]); xf[rt][ks][4 + j] = f2bf(bb[j]); }
        }
    }

    // --- expert0 weights ---
    bf16x8 wa0[2][8], wb0[4][2];
    #pragma unroll
    for (int ks = 0; ks < 2; ++ks)
        #pragma unroll
        for (int nt = 0; nt < 8; ++nt) wa0[ks][nt] = frag[(ks * 8 + nt) * 64 + l];
    #pragma unroll
    for (int ks = 0; ks < 4; ++ks)
        #pragma unroll
        for (int ot = 0; ot < 2; ++ot) wb0[ks][ot] = frag[(16 + ks * 2 + ot) * 64 + l];

    // --- phase A: MLP0 per tile, masked bf16 store to out0b ---
    #pragma unroll
    for (int rt = 0; rt < 4; ++rt) {
        f32x4 acc1[8];
        #pragma unroll
        for (int nt = 0; nt < 8; ++nt) acc1[nt] = *(const f32x4*)(b0a + 16 * nt + 4 * g);
        #pragma unroll
        for (int ks = 0; ks < 2; ++ks)
            #pragma unroll
            for (int nt = 0; nt < 8; ++nt) acc1[nt] = MFMA(wa0[ks][nt], xf[rt][ks], acc1[nt]);

        bf16x8 hf[4];
        #pragma unroll
        for (int k2 = 0; k2 < 4; ++k2)
            #pragma unroll
            for (int j = 0; j < 8; ++j)
                hf[k2][j] = f2bf(fmaxf(acc1[2 * k2 + (j >> 2)][j & 3], 0.0f));

        f32x4 acc2[2];
        #pragma unroll
        for (int ot = 0; ot < 2; ++ot) acc2[ot] = *(const f32x4*)(b0b + 16 * ot + 4 * g);
        #pragma unroll
        for (int k2 = 0; k2 < 4; ++k2)
            #pragma unroll
            for (int ot = 0; ot < 2; ++ot) acc2[ot] = MFMA(wb0[k2][ot], hf[k2], acc2[ot]);

        const int row = b * RPB + wv * 64 + rt * 16 + c;
        const int2 tk = ((const int2*)topk)[row];
        const bool m0 = (tk.x == 0) || (tk.y == 0);
        #pragma unroll
        for (int ot = 0; ot < 2; ++ot) {
            bf16x4 v;
            #pragma unroll
            for (int j = 0; j < 4; ++j) v[j] = f2bf(m0 ? acc2[ot][j] : 0.0f);
            *(bf16x4*)(out0b + (size_t)row * 32 + 16 * ot + 4 * g) = v;
        }
    }

    __syncthreads();   // S1: all out0b stores drained; smax/wtot visible

    // --- expert1 weights (issued now so they overlap the publish/lookback) ---
    bf16x8 wa1[3][8], wb1[4][2];
    #pragma unroll
    for (int ks = 0; ks < 3; ++ks)
        #pragma unroll
        for (int nt = 0; nt < 8; ++nt) wa1[ks][nt] = frag[(24 + ks * 8 + nt) * 64 + l];
    #pragma unroll
    for (int ks = 0; ks < 4; ++ks)
        #pragma unroll
        for (int ot = 0; ot < 2; ++ot) wb1[ks][ot] = frag[(48 + ks * 2 + ot) * 64 + l];

    // --- publish agg + resolve exclusive prefix (single hop in practice) ---
    if (tid == 0) {
        const int agg = max(max(smax[0], smax[1]), max(smax[2], smax[3]));
        __hip_atomic_store(&state[b], PUBLISHED | (unsigned)agg,
                           __ATOMIC_RELEASE, __HIP_MEMORY_SCOPE_AGENT);
        int excl = 0;
        for (int p = b - 1; p >= 0; --p) {
            unsigned st;
            do {
                st = __hip_atomic_load(&state[p], __ATOMIC_ACQUIRE, __HIP_MEMORY_SCOPE_AGENT);
            } while (!(st & PUBLISHED));
            const int v = (int)(st & 0x7FFFFFFFu);
            if (v) { excl = v; break; }   // nonzero agg dominates all earlier chunks
        }
        sExcl = excl;
    }
    __syncthreads();   // S2

    int pre = sExcl;
    #pragma unroll
    for (int w2 = 0; w2 < 4; ++w2)
        if (w2 < wv) pre = max(pre, wtot[w2]);
    const int sidx = max(pre, s);          // global inclusive cummax for row t

    // --- phase B: gather filled, MLP1, blend, store ---
    #pragma unroll
    for (int rt = 0; rt < 4; ++rt) {
        const int row = b * RPB + wv * 64 + rt * 16 + c;
        const int idxc = __shfl(sidx, rt * 16 + c, 64);

        bf16x8 xf2;
        {
            const unsigned short* fr = out0b + (size_t)idxc * 32;
            bf16x4 fa = *(const bf16x4*)(fr + 4 * g);
            bf16x4 fb = *(const bf16x4*)(fr + 16 + 4 * g);
            #pragma unroll
            for (int j = 0; j < 4; ++j) { xf2[j] = fa[j]; xf2[4 + j] = fb[j]; }
        }

        f32x4 acc1[8];
        #pragma unroll
        for (int nt = 0; nt < 8; ++nt) acc1[nt] = *(const f32x4*)(b1a + 16 * nt + 4 * g);
        #pragma unroll
        for (int ks = 0; ks < 2; ++ks)
            #pragma unroll
            for (int nt = 0; nt < 8; ++nt) acc1[nt] = MFMA(wa1[ks][nt], xf[rt][ks], acc1[nt]);
        #pragma unroll
        for (int nt = 0; nt < 8; ++nt) acc1[nt] = MFMA(wa1[2][nt], xf2, acc1[nt]);

        bf16x8 hf[4];
        #pragma unroll
        for (int k2 = 0; k2 < 4; ++k2)
            #pragma unroll
            for (int j = 0; j < 8; ++j)
                hf[k2][j] = f2bf(fmaxf(acc1[2 * k2 + (j >> 2)][j & 3], 0.0f));

        f32x4 acc2[2];
        #pragma unroll
        for (int ot = 0; ot < 2; ++ot) acc2[ot] = *(const f32x4*)(b1b + 16 * ot + 4 * g);
        #pragma unroll
        for (int k2 = 0; k2 < 4; ++k2)
            #pragma unroll
            for (int ot = 0; ot < 2; ++ot) acc2[ot] = MFMA(wb1[k2][ot], hf[k2], acc2[ot]);

        const int2 tk = ((const int2*)topk)[row];
        const bool m1 = (tk.x == 1) || (tk.y == 1);
        const float w  = wts[(size_t)row * 2];
        const float wc = 1.0f - w;
        #pragma unroll
        for (int ot = 0; ot < 2; ++ot) {
            bf16x4 oa = *(const bf16x4*)(out0b + (size_t)row * 32 + 16 * ot + 4 * g);
            f32x4 r;
            #pragma unroll
            for (int j = 0; j < 4; ++j) {
                const float e1 = m1 ? acc2[ot][j] : 0.0f;
                r[j] = w * bf2f(oa[j]) + wc * e1;
            }
            *(f32x4*)(out + (size_t)row * 32 + 16 * ot + 4 * g) = r;
        }
    }
}

// ---------------------------------------------------------------------------
extern "C" void kernel_launch(void* const* d_in, const int* in_sizes, int n_in,
                              void* d_out, int out_size, void* d_ws, size_t ws_size,
                              hipStream_t stream)
{
    const float* x    = (const float*)d_in[0];
    const int*   topk = (const int*)  d_in[1];
    const float* wts  = (const float*)d_in[2];
    const float* W0a  = (const float*)d_in[3];
    const float* b0a  = (const float*)d_in[4];
    const float* W0b  = (const float*)d_in[5];
    const float* b0b  = (const float*)d_in[6];
    const float* W1a  = (const float*)d_in[7];
    const float* b1a  = (const float*)d_in[8];
    const float* W1b  = (const float*)d_in[9];
    const float* b1b  = (const float*)d_in[10];
    float* out = (float*)d_out;

    // ws layout: [frag 56KiB][state 16KiB][out0b: T*32 bf16 = 64MiB]
    bf16x8*         frag  = (bf16x8*)d_ws;
    unsigned*       state = (unsigned*)((char*)d_ws + 56 * 1024);
    unsigned short* out0b = (unsigned short*)((char*)d_ws + 72 * 1024);

    hipMemsetAsync(state, 0, NCHUNK * sizeof(unsigned), stream);
    prep_kernel<<<dim3(56), dim3(64), 0, stream>>>(W0a, W0b, W1a, W1b, frag);
    fused_kernel<<<dim3(NCHUNK), dim3(RPB), 0, stream>>>(
        x, topk, wts, b0a, b0b, b1a, b1b, frag, state, out0b, out);
}

// Round 4
// 238.295 us; speedup vs baseline: 1.6536x; 1.6536x over previous
//
#include <hip/hip_runtime.h>
#include <hip/hip_bf16.h>

#define TROWS 1048576
#define RPB   256                    // rows per block (chunk)
#define NCHUNK (TROWS / RPB)         // 4096
#define LSTRIDE 36                   // LDS row stride in shorts (72 B, 8B-aligned, conflict-free-ish)

typedef float f32x4  __attribute__((ext_vector_type(4)));
typedef short bf16x8 __attribute__((ext_vector_type(8)));
typedef short bf16x4 __attribute__((ext_vector_type(4)));

#define MFMA(a, b, c) __builtin_amdgcn_mfma_f32_16x16x32_bf16(a, b, c, 0, 0, 0)

__device__ __forceinline__ short f2bf(float v) {
    __hip_bfloat16 b = __float2bfloat16(v);
    return __builtin_bit_cast(short, b);
}
__device__ __forceinline__ float bf2f(short s) {
    unsigned u = ((unsigned)(unsigned short)s) << 16;
    return __builtin_bit_cast(float, u);
}

// k-map for ALL A/B fragments: kappa(g,j) = j<4 ? 4g+j : 16+4g+(j-4)
// ---------------------------------------------------------------------------
// Prep: weights -> bf16 fragment order (verified rounds 2-3).
//   W0a: frag 0..15 (ks*8+nt)   W0b: 16..23 (ks*2+ot)
//   W1a: 24..47 (ks*8+nt)       W1b: 48..55 (ks*2+ot)
// ---------------------------------------------------------------------------
__global__ __launch_bounds__(64) void prep_kernel(
    const float* __restrict__ W0a, const float* __restrict__ W0b,
    const float* __restrict__ W1a, const float* __restrict__ W1b,
    bf16x8* __restrict__ frag)
{
    const int fid = blockIdx.x, l = threadIdx.x, c = l & 15, g = l >> 4;
    const float* W; int N, ks, nt;
    if (fid < 16)      { W = W0a; N = 128; ks = fid >> 3;        nt = fid & 7; }
    else if (fid < 24) { W = W0b; N = 32;  ks = (fid - 16) >> 1; nt = (fid - 16) & 1; }
    else if (fid < 48) { W = W1a; N = 128; ks = (fid - 24) >> 3; nt = (fid - 24) & 7; }
    else               { W = W1b; N = 32;  ks = (fid - 48) >> 1; nt = (fid - 48) & 1; }
    bf16x8 f;
    #pragma unroll
    for (int j = 0; j < 8; ++j) {
        const int k = 32 * ks + ((j < 4) ? (4 * g + j) : (16 + 4 * g + (j - 4)));
        f[j] = f2bf(W[k * N + 16 * nt + c]);
    }
    frag[fid * 64 + l] = f;
}

// ---------------------------------------------------------------------------
// Fused kernel, ZERO inter-block communication:
//   - backward topk-scan finds p = last mask0 row before this chunk (input-only)
//   - phase A: MLP0 for 256 own rows -> LDS (bf16, masked); wave 0 additionally
//     computes the p-row tile (broadcast) -> LDS slot 256
//   - phase B: idx from in-block cummax (or p); gather filled from LDS;
//     MLP1; blend; store out. x fragments live in VGPRs across both phases.
// ---------------------------------------------------------------------------
__global__ __launch_bounds__(256) void fused_kernel(
    const float* __restrict__ x, const int* __restrict__ topk,
    const float* __restrict__ wts,
    const float* __restrict__ b0a, const float* __restrict__ b0b,
    const float* __restrict__ b1a, const float* __restrict__ b1b,
    const bf16x8* __restrict__ frag,
    float* __restrict__ out)
{
    const int b = blockIdx.x;
    const int tid = threadIdx.x, wv = tid >> 6, l = tid & 63, c = l & 15, g = l >> 4;

    __shared__ short out0_lds[257 * LSTRIDE];   // 18.5 KB
    __shared__ int wtot[4];

    // --- own-row inclusive wave cummax of (mask0 ? t : 0) ---
    const int t = b * RPB + tid;
    const int2 tko = ((const int2*)topk)[t];
    const bool m0o = (tko.x == 0) || (tko.y == 0);
    int s = m0o ? t : 0;
    #pragma unroll
    for (int off = 1; off < 64; off <<= 1) {
        int u = __shfl_up(s, off, 64);
        if (l >= off) s = max(s, u);
    }
    if (l == 63) wtot[wv] = s;

    // --- backward scan for p = last mask0 row < 256b (every wave, redundant) ---
    int p = 0;
    for (int base = b * RPB - 64; base >= 0; base -= 64) {
        const int2 tkq = ((const int2*)topk)[base + l];
        const bool mm = (tkq.x == 0) || (tkq.y == 0);
        const unsigned long long bal = __ballot(mm);
        if (bal) { p = base + 63 - __clzll(bal); break; }
    }
    const int2 tkp = ((const int2*)topk)[p];
    const bool m0p = (tkp.x == 0) || (tkp.y == 0);   // false only if no mask0 row exists at all

    // --- load x fragments for own 4 row-tiles (the only x read) ---
    bf16x8 xf[4][2];
    #pragma unroll
    for (int rt = 0; rt < 4; ++rt) {
        const int row = b * RPB + wv * 64 + rt * 16 + c;
        const float* xr = x + (size_t)row * 64;
        #pragma unroll
        for (int ks = 0; ks < 2; ++ks) {
            f32x4 a  = *(const f32x4*)(xr + 32 * ks + 4 * g);
            f32x4 bb = *(const f32x4*)(xr + 32 * ks + 16 + 4 * g);
            #pragma unroll
            for (int j = 0; j < 4; ++j) { xf[rt][ks][j] = f2bf(a[j]); xf[rt][ks][4 + j] = f2bf(bb[j]); }
        }
    }

    // --- expert0 weights ---
    bf16x8 wa0[2][8], wb0[4][2];
    #pragma unroll
    for (int ks = 0; ks < 2; ++ks)
        #pragma unroll
        for (int nt = 0; nt < 8; ++nt) wa0[ks][nt] = frag[(ks * 8 + nt) * 64 + l];
    #pragma unroll
    for (int ks = 0; ks < 4; ++ks)
        #pragma unroll
        for (int ot = 0; ot < 2; ++ot) wb0[ks][ot] = frag[(16 + ks * 2 + ot) * 64 + l];

    // --- phase A: MLP0 per tile -> masked bf16 to LDS ---
    #pragma unroll
    for (int rt = 0; rt < 4; ++rt) {
        f32x4 acc1[8];
        #pragma unroll
        for (int nt = 0; nt < 8; ++nt) acc1[nt] = *(const f32x4*)(b0a + 16 * nt + 4 * g);
        #pragma unroll
        for (int ks = 0; ks < 2; ++ks)
            #pragma unroll
            for (int nt = 0; nt < 8; ++nt) acc1[nt] = MFMA(wa0[ks][nt], xf[rt][ks], acc1[nt]);

        bf16x8 hf[4];
        #pragma unroll
        for (int k2 = 0; k2 < 4; ++k2)
            #pragma unroll
            for (int j = 0; j < 8; ++j)
                hf[k2][j] = f2bf(fmaxf(acc1[2 * k2 + (j >> 2)][j & 3], 0.0f));

        f32x4 acc2[2];
        #pragma unroll
        for (int ot = 0; ot < 2; ++ot) acc2[ot] = *(const f32x4*)(b0b + 16 * ot + 4 * g);
        #pragma unroll
        for (int k2 = 0; k2 < 4; ++k2)
            #pragma unroll
            for (int ot = 0; ot < 2; ++ot) acc2[ot] = MFMA(wb0[k2][ot], hf[k2], acc2[ot]);

        const int slot = wv * 64 + rt * 16 + c;
        const int2 tk = ((const int2*)topk)[b * RPB + slot];
        const bool m0 = (tk.x == 0) || (tk.y == 0);
        #pragma unroll
        for (int ot = 0; ot < 2; ++ot) {
            bf16x4 v;
            #pragma unroll
            for (int j = 0; j < 4; ++j) v[j] = f2bf(m0 ? acc2[ot][j] : 0.0f);
            *(bf16x4*)(&out0_lds[slot * LSTRIDE + 16 * ot + 4 * g]) = v;
        }
    }

    // --- wave 0: p-row tile (broadcast x[p] across all c) -> LDS slot 256 ---
    if (wv == 0) {
        const float* xp = x + (size_t)p * 64;
        bf16x8 xpf[2];
        #pragma unroll
        for (int ks = 0; ks < 2; ++ks) {
            f32x4 a  = *(const f32x4*)(xp + 32 * ks + 4 * g);
            f32x4 bb = *(const f32x4*)(xp + 32 * ks + 16 + 4 * g);
            #pragma unroll
            for (int j = 0; j < 4; ++j) { xpf[ks][j] = f2bf(a[j]); xpf[ks][4 + j] = f2bf(bb[j]); }
        }
        f32x4 acc1[8];
        #pragma unroll
        for (int nt = 0; nt < 8; ++nt) acc1[nt] = *(const f32x4*)(b0a + 16 * nt + 4 * g);
        #pragma unroll
        for (int ks = 0; ks < 2; ++ks)
            #pragma unroll
            for (int nt = 0; nt < 8; ++nt) acc1[nt] = MFMA(wa0[ks][nt], xpf[ks], acc1[nt]);
        bf16x8 hf[4];
        #pragma unroll
        for (int k2 = 0; k2 < 4; ++k2)
            #pragma unroll
            for (int j = 0; j < 8; ++j)
                hf[k2][j] = f2bf(fmaxf(acc1[2 * k2 + (j >> 2)][j & 3], 0.0f));
        f32x4 acc2[2];
        #pragma unroll
        for (int ot = 0; ot < 2; ++ot) acc2[ot] = *(const f32x4*)(b0b + 16 * ot + 4 * g);
        #pragma unroll
        for (int k2 = 0; k2 < 4; ++k2)
            #pragma unroll
            for (int ot = 0; ot < 2; ++ot) acc2[ot] = MFMA(wb0[k2][ot], hf[k2], acc2[ot]);
        if (c == 0) {
            #pragma unroll
            for (int ot = 0; ot < 2; ++ot) {
                bf16x4 v;
                #pragma unroll
                for (int j = 0; j < 4; ++j) v[j] = f2bf(m0p ? acc2[ot][j] : 0.0f);
                *(bf16x4*)(&out0_lds[256 * LSTRIDE + 16 * ot + 4 * g]) = v;
            }
        }
    }

    // --- expert1 weights (issue overlapping the barrier) ---
    bf16x8 wa1[3][8], wb1[4][2];
    #pragma unroll
    for (int ks = 0; ks < 3; ++ks)
        #pragma unroll
        for (int nt = 0; nt < 8; ++nt) wa1[ks][nt] = frag[(24 + ks * 8 + nt) * 64 + l];
    #pragma unroll
    for (int ks = 0; ks < 4; ++ks)
        #pragma unroll
        for (int ot = 0; ot < 2; ++ot) wb1[ks][ot] = frag[(48 + ks * 2 + ot) * 64 + l];

    __syncthreads();   // LDS out0 complete; wtot visible

    // --- in-chunk inclusive cummax for own row ---
    int pre = 0;
    #pragma unroll
    for (int w2 = 0; w2 < 4; ++w2)
        if (w2 < wv) pre = max(pre, wtot[w2]);
    const int s_full = max(pre, s);       // 0 if no mask0 row <= t in chunk

    // --- phase B: gather filled from LDS, MLP1, blend, store ---
    #pragma unroll
    for (int rt = 0; rt < 4; ++rt) {
        const int row = b * RPB + wv * 64 + rt * 16 + c;
        const int sF = __shfl(s_full, rt * 16 + c, 64);
        const int slot = (sF > 0) ? (sF - b * RPB) : 256;

        bf16x8 xf2;
        {
            const short* fr = &out0_lds[slot * LSTRIDE];
            bf16x4 fa = *(const bf16x4*)(fr + 4 * g);
            bf16x4 fb = *(const bf16x4*)(fr + 16 + 4 * g);
            #pragma unroll
            for (int j = 0; j < 4; ++j) { xf2[j] = fa[j]; xf2[4 + j] = fb[j]; }
        }

        f32x4 acc1[8];
        #pragma unroll
        for (int nt = 0; nt < 8; ++nt) acc1[nt] = *(const f32x4*)(b1a + 16 * nt + 4 * g);
        #pragma unroll
        for (int ks = 0; ks < 2; ++ks)
            #pragma unroll
            for (int nt = 0; nt < 8; ++nt) acc1[nt] = MFMA(wa1[ks][nt], xf[rt][ks], acc1[nt]);
        #pragma unroll
        for (int nt = 0; nt < 8; ++nt) acc1[nt] = MFMA(wa1[2][nt], xf2, acc1[nt]);

        bf16x8 hf[4];
        #pragma unroll
        for (int k2 = 0; k2 < 4; ++k2)
            #pragma unroll
            for (int j = 0; j < 8; ++j)
                hf[k2][j] = f2bf(fmaxf(acc1[2 * k2 + (j >> 2)][j & 3], 0.0f));

        f32x4 acc2[2];
        #pragma unroll
        for (int ot = 0; ot < 2; ++ot) acc2[ot] = *(const f32x4*)(b1b + 16 * ot + 4 * g);
        #pragma unroll
        for (int k2 = 0; k2 < 4; ++k2)
            #pragma unroll
            for (int ot = 0; ot < 2; ++ot) acc2[ot] = MFMA(wb1[k2][ot], hf[k2], acc2[ot]);

        const int2 tk = ((const int2*)topk)[row];
        const bool m1 = (tk.x == 1) || (tk.y == 1);
        const float w  = wts[(size_t)row * 2];
        const float wc = 1.0f - w;
        const int oslot = wv * 64 + rt * 16 + c;
        #pragma unroll
        for (int ot = 0; ot < 2; ++ot) {
            bf16x4 oa = *(const bf16x4*)(&out0_lds[oslot * LSTRIDE + 16 * ot + 4 * g]);
            f32x4 r;
            #pragma unroll
            for (int j = 0; j < 4; ++j) {
                const float e1 = m1 ? acc2[ot][j] : 0.0f;
                r[j] = w * bf2f(oa[j]) + wc * e1;
            }
            *(f32x4*)(out + (size_t)row * 32 + 16 * ot + 4 * g) = r;
        }
    }
}

// ---------------------------------------------------------------------------
extern "C" void kernel_launch(void* const* d_in, const int* in_sizes, int n_in,
                              void* d_out, int out_size, void* d_ws, size_t ws_size,
                              hipStream_t stream)
{
    const float* x    = (const float*)d_in[0];
    const int*   topk = (const int*)  d_in[1];
    const float* wts  = (const float*)d_in[2];
    const float* W0a  = (const float*)d_in[3];
    const float* b0a  = (const float*)d_in[4];
    const float* W0b  = (const float*)d_in[5];
    const float* b0b  = (const float*)d_in[6];
    const float* W1a  = (const float*)d_in[7];
    const float* b1a  = (const float*)d_in[8];
    const float* W1b  = (const float*)d_in[9];
    const float* b1b  = (const float*)d_in[10];
    float* out = (float*)d_out;

    bf16x8* frag = (bf16x8*)d_ws;   // 56 KiB

    prep_kernel<<<dim3(56), dim3(64), 0, stream>>>(W0a, W0b, W1a, W1b, frag);
    fused_kernel<<<dim3(NCHUNK), dim3(RPB), 0, stream>>>(
        x, topk, wts, b0a, b0b, b1a, b1b, frag, out);
}

// Round 5
// 151.446 us; speedup vs baseline: 2.6019x; 1.5735x over previous
//
#include <hip/hip_runtime.h>
#include <hip/hip_bf16.h>

#define TROWS 1048576
#define RPB   256                    // rows per block (chunk)
#define NCHUNK (TROWS / RPB)         // 4096
#define LSTRIDE 36                   // LDS row stride in shorts (72 B)

typedef float f32x4  __attribute__((ext_vector_type(4)));
typedef short bf16x8 __attribute__((ext_vector_type(8)));
typedef short bf16x4 __attribute__((ext_vector_type(4)));

#define MFMA(a, b, c) __builtin_amdgcn_mfma_f32_16x16x32_bf16(a, b, c, 0, 0, 0)

__device__ __forceinline__ short f2bf(float v) {
    __hip_bfloat16 b = __float2bfloat16(v);
    return __builtin_bit_cast(short, b);
}
__device__ __forceinline__ float bf2f(short s) {
    unsigned u = ((unsigned)(unsigned short)s) << 16;
    return __builtin_bit_cast(float, u);
}

// k-map for ALL A/B fragments: kappa(g,j) = j<4 ? 4g+j : 16+4g+(j-4)
// ---------------------------------------------------------------------------
// Prep: weights -> bf16 fragment order (verified rounds 2-4).
//   W0a: frag 0..15 (ks*8+nt)   W0b: 16..23 (k2*2+ot)
//   W1a: 24..47 (ks*8+nt)       W1b: 48..55 (k2*2+ot)
// ---------------------------------------------------------------------------
__global__ __launch_bounds__(64) void prep_kernel(
    const float* __restrict__ W0a, const float* __restrict__ W0b,
    const float* __restrict__ W1a, const float* __restrict__ W1b,
    bf16x8* __restrict__ frag)
{
    const int fid = blockIdx.x, l = threadIdx.x, c = l & 15, g = l >> 4;
    const float* W; int N, ks, nt;
    if (fid < 16)      { W = W0a; N = 128; ks = fid >> 3;        nt = fid & 7; }
    else if (fid < 24) { W = W0b; N = 32;  ks = (fid - 16) >> 1; nt = (fid - 16) & 1; }
    else if (fid < 48) { W = W1a; N = 128; ks = (fid - 24) >> 3; nt = (fid - 24) & 7; }
    else               { W = W1b; N = 32;  ks = (fid - 48) >> 1; nt = (fid - 48) & 1; }
    bf16x8 f;
    #pragma unroll
    for (int j = 0; j < 8; ++j) {
        const int k = 32 * ks + ((j < 4) ? (4 * g + j) : (16 + 4 * g + (j - 4)));
        f[j] = f2bf(W[k * N + 16 * nt + c]);
    }
    frag[fid * 64 + l] = f;
}

// ---------------------------------------------------------------------------
// Fused kernel, k2-pipelined frag reuse:
//   phase A: for k2: {load 4 wa0 + 2 wb0 frags, apply to 5 tiles (4 own + p)}
//   phase B: for k2: {load 6 wa1 + 2 wb1 frags, apply to 4 tiles}
//   Weight frags loaded ONCE per k2 per wave (4x less L2 traffic than r4).
// ---------------------------------------------------------------------------
__global__ __launch_bounds__(256) void fused_kernel(
    const float* __restrict__ x, const int* __restrict__ topk,
    const float* __restrict__ wts,
    const float* __restrict__ b0a, const float* __restrict__ b0b,
    const float* __restrict__ b1a, const float* __restrict__ b1b,
    const bf16x8* __restrict__ frag,
    float* __restrict__ out)
{
    const int b = blockIdx.x;
    const int tid = threadIdx.x, wv = tid >> 6, l = tid & 63, c = l & 15, g = l >> 4;

    __shared__ short out0_lds[257 * LSTRIDE];   // 18.5 KB
    __shared__ int wtot[4];

    // --- own-row inclusive wave cummax of (mask0 ? t : 0) ---
    const int t = b * RPB + tid;
    const int2 tko = ((const int2*)topk)[t];
    const bool m0o = (tko.x == 0) || (tko.y == 0);
    int s = m0o ? t : 0;
    #pragma unroll
    for (int off = 1; off < 64; off <<= 1) {
        int u = __shfl_up(s, off, 64);
        if (l >= off) s = max(s, u);
    }
    if (l == 63) wtot[wv] = s;

    // --- backward scan for p = last mask0 row < 256b (input-only) ---
    int p = 0;
    for (int base = b * RPB - 64; base >= 0; base -= 64) {
        const int2 tkq = ((const int2*)topk)[base + l];
        const bool mm = (tkq.x == 0) || (tkq.y == 0);
        const unsigned long long bal = __ballot(mm);
        if (bal) { p = base + 63 - __clzll(bal); break; }
    }
    const int2 tkp = ((const int2*)topk)[p];
    const bool m0p = (tkp.x == 0) || (tkp.y == 0);

    // --- x fragments: own 4 tiles + p-row broadcast (the only x reads) ---
    bf16x8 xf[4][2];
    #pragma unroll
    for (int rt = 0; rt < 4; ++rt) {
        const int row = b * RPB + wv * 64 + rt * 16 + c;
        const float* xr = x + (size_t)row * 64;
        #pragma unroll
        for (int ks = 0; ks < 2; ++ks) {
            f32x4 a  = *(const f32x4*)(xr + 32 * ks + 4 * g);
            f32x4 bb = *(const f32x4*)(xr + 32 * ks + 16 + 4 * g);
            #pragma unroll
            for (int j = 0; j < 4; ++j) { xf[rt][ks][j] = f2bf(a[j]); xf[rt][ks][4 + j] = f2bf(bb[j]); }
        }
    }
    bf16x8 xfp[2];
    {
        const float* xp = x + (size_t)p * 64;
        #pragma unroll
        for (int ks = 0; ks < 2; ++ks) {
            f32x4 a  = *(const f32x4*)(xp + 32 * ks + 4 * g);
            f32x4 bb = *(const f32x4*)(xp + 32 * ks + 16 + 4 * g);
            #pragma unroll
            for (int j = 0; j < 4; ++j) { xfp[ks][j] = f2bf(a[j]); xfp[ks][4 + j] = f2bf(bb[j]); }
        }
    }

    // ---- phase A: MLP0, k2-pipelined, 5 tiles share each frag load ----
    f32x4 acc2a[5][2];
    {
        f32x4 bi0 = *(const f32x4*)(b0b + 4 * g);
        f32x4 bi1 = *(const f32x4*)(b0b + 16 + 4 * g);
        #pragma unroll
        for (int rt = 0; rt < 5; ++rt) { acc2a[rt][0] = bi0; acc2a[rt][1] = bi1; }
    }
    #pragma unroll
    for (int k2 = 0; k2 < 4; ++k2) {
        bf16x8 fa[2][2];
        #pragma unroll
        for (int ks = 0; ks < 2; ++ks)
            #pragma unroll
            for (int ntl = 0; ntl < 2; ++ntl)
                fa[ks][ntl] = frag[(ks * 8 + 2 * k2 + ntl) * 64 + l];
        f32x4 bi[2];
        bi[0] = *(const f32x4*)(b0a + 16 * (2 * k2) + 4 * g);
        bi[1] = *(const f32x4*)(b0a + 16 * (2 * k2 + 1) + 4 * g);

        f32x4 a1[5][2];
        #pragma unroll
        for (int rt = 0; rt < 5; ++rt) { a1[rt][0] = bi[0]; a1[rt][1] = bi[1]; }
        #pragma unroll
        for (int rt = 0; rt < 5; ++rt)
            #pragma unroll
            for (int ks = 0; ks < 2; ++ks) {
                const bf16x8 xv = (rt < 4) ? xf[rt][ks] : xfp[ks];
                a1[rt][0] = MFMA(fa[ks][0], xv, a1[rt][0]);
                a1[rt][1] = MFMA(fa[ks][1], xv, a1[rt][1]);
            }

        bf16x8 fb[2];
        fb[0] = frag[(16 + k2 * 2 + 0) * 64 + l];
        fb[1] = frag[(16 + k2 * 2 + 1) * 64 + l];
        #pragma unroll
        for (int rt = 0; rt < 5; ++rt) {
            bf16x8 hf;
            #pragma unroll
            for (int j = 0; j < 8; ++j)
                hf[j] = f2bf(fmaxf(a1[rt][j >> 2][j & 3], 0.0f));
            acc2a[rt][0] = MFMA(fb[0], hf, acc2a[rt][0]);
            acc2a[rt][1] = MFMA(fb[1], hf, acc2a[rt][1]);
        }
    }

    // --- store own tiles (masked) + p slot to LDS ---
    #pragma unroll
    for (int rt = 0; rt < 4; ++rt) {
        const int slot = wv * 64 + rt * 16 + c;
        const int2 tk = ((const int2*)topk)[b * RPB + slot];
        const bool m0 = (tk.x == 0) || (tk.y == 0);
        #pragma unroll
        for (int ot = 0; ot < 2; ++ot) {
            bf16x4 v;
            #pragma unroll
            for (int j = 0; j < 4; ++j) v[j] = f2bf(m0 ? acc2a[rt][ot][j] : 0.0f);
            *(bf16x4*)(&out0_lds[slot * LSTRIDE + 16 * ot + 4 * g]) = v;
        }
    }
    if (wv == 0 && c == 0) {
        #pragma unroll
        for (int ot = 0; ot < 2; ++ot) {
            bf16x4 v;
            #pragma unroll
            for (int j = 0; j < 4; ++j) v[j] = f2bf(m0p ? acc2a[4][ot][j] : 0.0f);
            *(bf16x4*)(&out0_lds[256 * LSTRIDE + 16 * ot + 4 * g]) = v;
        }
    }

    __syncthreads();   // LDS out0 complete; wtot visible

    // --- in-chunk inclusive cummax + gather filled frags ---
    int pre = 0;
    #pragma unroll
    for (int w2 = 0; w2 < 4; ++w2)
        if (w2 < wv) pre = max(pre, wtot[w2]);
    const int s_full = max(pre, s);

    bf16x8 xf2[4];
    #pragma unroll
    for (int rt = 0; rt < 4; ++rt) {
        const int sF = __shfl(s_full, rt * 16 + c, 64);
        const int slot = (sF > 0) ? (sF - b * RPB) : 256;
        const short* fr = &out0_lds[slot * LSTRIDE];
        bf16x4 fa_ = *(const bf16x4*)(fr + 4 * g);
        bf16x4 fb_ = *(const bf16x4*)(fr + 16 + 4 * g);
        #pragma unroll
        for (int j = 0; j < 4; ++j) { xf2[rt][j] = fa_[j]; xf2[rt][4 + j] = fb_[j]; }
    }

    // ---- phase B: MLP1, k2-pipelined, 4 tiles share each frag load ----
    f32x4 acc2b[4][2];
    {
        f32x4 bi0 = *(const f32x4*)(b1b + 4 * g);
        f32x4 bi1 = *(const f32x4*)(b1b + 16 + 4 * g);
        #pragma unroll
        for (int rt = 0; rt < 4; ++rt) { acc2b[rt][0] = bi0; acc2b[rt][1] = bi1; }
    }
    #pragma unroll
    for (int k2 = 0; k2 < 4; ++k2) {
        bf16x8 fa[3][2];
        #pragma unroll
        for (int ks = 0; ks < 3; ++ks)
            #pragma unroll
            for (int ntl = 0; ntl < 2; ++ntl)
                fa[ks][ntl] = frag[(24 + ks * 8 + 2 * k2 + ntl) * 64 + l];
        f32x4 bi[2];
        bi[0] = *(const f32x4*)(b1a + 16 * (2 * k2) + 4 * g);
        bi[1] = *(const f32x4*)(b1a + 16 * (2 * k2 + 1) + 4 * g);

        f32x4 a1[4][2];
        #pragma unroll
        for (int rt = 0; rt < 4; ++rt) { a1[rt][0] = bi[0]; a1[rt][1] = bi[1]; }
        #pragma unroll
        for (int rt = 0; rt < 4; ++rt) {
            #pragma unroll
            for (int ks = 0; ks < 2; ++ks) {
                a1[rt][0] = MFMA(fa[ks][0], xf[rt][ks], a1[rt][0]);
                a1[rt][1] = MFMA(fa[ks][1], xf[rt][ks], a1[rt][1]);
            }
            a1[rt][0] = MFMA(fa[2][0], xf2[rt], a1[rt][0]);
            a1[rt][1] = MFMA(fa[2][1], xf2[rt], a1[rt][1]);
        }

        bf16x8 fb[2];
        fb[0] = frag[(48 + k2 * 2 + 0) * 64 + l];
        fb[1] = frag[(48 + k2 * 2 + 1) * 64 + l];
        #pragma unroll
        for (int rt = 0; rt < 4; ++rt) {
            bf16x8 hf;
            #pragma unroll
            for (int j = 0; j < 8; ++j)
                hf[j] = f2bf(fmaxf(a1[rt][j >> 2][j & 3], 0.0f));
            acc2b[rt][0] = MFMA(fb[0], hf, acc2b[rt][0]);
            acc2b[rt][1] = MFMA(fb[1], hf, acc2b[rt][1]);
        }
    }

    // --- blend + store ---
    #pragma unroll
    for (int rt = 0; rt < 4; ++rt) {
        const int row = b * RPB + wv * 64 + rt * 16 + c;
        const int2 tk = ((const int2*)topk)[row];
        const bool m1 = (tk.x == 1) || (tk.y == 1);
        const float w  = wts[(size_t)row * 2];
        const float wc = 1.0f - w;
        const int oslot = wv * 64 + rt * 16 + c;
        #pragma unroll
        for (int ot = 0; ot < 2; ++ot) {
            bf16x4 oa = *(const bf16x4*)(&out0_lds[oslot * LSTRIDE + 16 * ot + 4 * g]);
            f32x4 r;
            #pragma unroll
            for (int j = 0; j < 4; ++j) {
                const float e1 = m1 ? acc2b[rt][ot][j] : 0.0f;
                r[j] = w * bf2f(oa[j]) + wc * e1;
            }
            *(f32x4*)(out + (size_t)row * 32 + 16 * ot + 4 * g) = r;
        }
    }
}

// ---------------------------------------------------------------------------
extern "C" void kernel_launch(void* const* d_in, const int* in_sizes, int n_in,
                              void* d_out, int out_size, void* d_ws, size_t ws_size,
                              hipStream_t stream)
{
    const float* x    = (const float*)d_in[0];
    const int*   topk = (const int*)  d_in[1];
    const float* wts  = (const float*)d_in[2];
    const float* W0a  = (const float*)d_in[3];
    const float* b0a  = (const float*)d_in[4];
    const float* W0b  = (const float*)d_in[5];
    const float* b0b  = (const float*)d_in[6];
    const float* W1a  = (const float*)d_in[7];
    const float* b1a  = (const float*)d_in[8];
    const float* W1b  = (const float*)d_in[9];
    const float* b1b  = (const float*)d_in[10];
    float* out = (float*)d_out;

    bf16x8* frag = (bf16x8*)d_ws;   // 56 KiB

    prep_kernel<<<dim3(56), dim3(64), 0, stream>>>(W0a, W0b, W1a, W1b, frag);
    fused_kernel<<<dim3(NCHUNK), dim3(RPB), 0, stream>>>(
        x, topk, wts, b0a, b0b, b1a, b1b, frag, out);
}